// Round 4
// baseline (178.251 us; speedup 1.0000x reference)
//
#include <hip/hip_runtime.h>
#include <cstddef>
#include <cstdint>

// SpatialEmbLoss on MI355X.
// H=W=768, 2 images, NC=5 classes, MAX_ID=3 -> 15 (class,id) pairs per image.
// Lovasz hinge via 2048-bin error histogram:
//   lov = integral_0^2 jac(t) dt,  jac(t) = 1 - (gts - n_in(t))/(gts + n_out(t))
// Round 4: occupancy. k_hist 24.5KB LDS capped at 6 blk/CU (41% meas) -> single
// hout copy, 16.4KB -> 8 blk/CU (wave-limited). k_pass1/k_argmin 1.5/1.1 blk/CU
// -> 4.5 blk/CU via 4px/thread float4 loads; fast tanh/sigmoid (__expf). k_final
// folded into last k_lovasz block (device-scope atomics).

#define HH 768
#define WW 768
#define NPIX (HH*WW)            // 589824
#define NCL 5
#define MAXID 3
#define PAIRS (NCL*MAXID)       // 15
#define NIMG 2
#define NCH 9                   // 2 emb + 2 sigma + 5 seed channels
#define BINS 2048
#define PXB 8192                // pixels per k_hist block
#define NB5 (NPIX/PXB)          // 72 chunks per (img,pair)

struct WS {
  unsigned long long argkey[NIMG][PAIRS];   // init 0xFF (atomicMin keys)
  // ---------- zero region from here ----------
  unsigned int cnt[NIMG][PAIRS];            // written by k_medoid (colhist total)
  unsigned int lovdone;                     // k_lovasz completion counter
  unsigned int colhist[NIMG][PAIRS][WW];
  unsigned int rowhist[NIMG][PAIRS][HH];
  float sigsum0[NIMG][PAIRS];
  float sigsum1[NIMG][PAIRS];
  float seedT[NIMG];            // sum over pixels,classes of sigmoid^2
  float seedOwn[NIMG];          // sum over pixels of own-class sigmoid^2
  alignas(8) unsigned int hin[NIMG][PAIRS][BINS];
  alignas(8) unsigned int hout[NIMG][PAIRS][BINS];
  float varsum[NIMG][PAIRS];
  float seedin[NIMG][PAIRS];
  float medx[NIMG][PAIRS], medy[NIMG][PAIRS];
  float s0a[NIMG][PAIRS], s1a[NIMG][PAIRS];
  float sm0a[NIMG][PAIRS], sm1a[NIMG][PAIRS];
  float validf[NIMG][PAIRS], cntf[NIMG][PAIRS];
  float lov[NIMG][PAIRS];
  // ---------- end zero region ----------
  alignas(16) float2 emb[NIMG][NPIX];      // {tanh(p0)+x, tanh(p1)+y}
  unsigned char pridx[NIMG][NPIX];         // pair index 0..14, 255 = none
};

__device__ __forceinline__ float basef(int i) {
  // jnp.linspace(0,1,1024)[i]
  return (float)i * (1.0f / 1023.0f);
}

__device__ __forceinline__ int pair_of(int l, int it) {
  return (l >= 1 && l <= NCL && it >= 1 && it <= MAXID) ? (l - 1) * MAXID + (it - 1) : -1;
}

__device__ __forceinline__ float fast_sigmoid(float z) {
  return __fdividef(1.f, 1.f + __expf(-z));
}
__device__ __forceinline__ float fast_tanh(float x) {
  float xc = fminf(fmaxf(x, -15.f), 15.f);
  float e = __expf(2.f * xc);
  return __fdividef(e - 1.f, e + 1.f);
}

// ---------------- pass 1: row/col hists, sigma sums, seed sums, emb+pridx precompute
// 1024 px per block (4 px/thread, float4/int4 channel loads), 1152 blocks.
__device__ __forceinline__ void px_work(int img, int x, int y, int rowoff, int l, int it,
    float z0, float z1, float g0, float g1,
    float s0z, float s1z, float s2z, float s3z, float s4z,
    WS* __restrict__ ws, float* ssig0, float* ssig1, unsigned int* srow,
    float& t, float& own, float& e0, float& e1, int& prOut) {
  float s, q;
  s = fast_sigmoid(s0z); q = s * s; t += q; if (l == 1) own += q;
  s = fast_sigmoid(s1z); q = s * s; t += q; if (l == 2) own += q;
  s = fast_sigmoid(s2z); q = s * s; t += q; if (l == 3) own += q;
  s = fast_sigmoid(s3z); q = s * s; t += q; if (l == 4) own += q;
  s = fast_sigmoid(s4z); q = s * s; t += q; if (l == 5) own += q;
  e0 = fast_tanh(z0) + basef(x);
  e1 = fast_tanh(z1) + basef(y);
  int pr = pair_of(l, it);
  prOut = pr;
  if (pr >= 0) {
    atomicAdd(&ssig0[pr], g0);
    atomicAdd(&ssig1[pr], g1);
    atomicAdd(&srow[rowoff * PAIRS + pr], 1u);
    atomicAdd(&ws->colhist[img][pr][x], 1u);
  }
}

__global__ __launch_bounds__(256) void k_pass1(const float* __restrict__ pred,
                                               const int* __restrict__ inst,
                                               const int* __restrict__ lab,
                                               WS* __restrict__ ws) {
  int img = blockIdx.y;
  int base = blockIdx.x * 1024;
  int tid = threadIdx.x;
  int pix0 = base + tid * 4;                 // 4-aligned; 768%4==0 -> same row
  const float* p = pred + (size_t)img * NCH * NPIX;

  __shared__ float ssig0[PAIRS], ssig1[PAIRS];
  __shared__ unsigned int srow[3 * PAIRS];
  __shared__ float sT, sO;
  if (tid < PAIRS) { ssig0[tid] = 0.f; ssig1[tid] = 0.f; }
  if (tid < 3 * PAIRS) srow[tid] = 0;
  if (tid == 0) { sT = 0.f; sO = 0.f; }
  __syncthreads();

  int ybase = base / WW;
  int y = pix0 / WW;
  int x0 = pix0 - y * WW;
  int rowoff = y - ybase;                    // 0..2

  int4 l4 = *(const int4*)(lab + (size_t)img * NPIX + pix0);
  int4 i4 = *(const int4*)(inst + (size_t)img * NPIX + pix0);
  float4 c0 = *(const float4*)(p + 0 * NPIX + pix0);
  float4 c1 = *(const float4*)(p + 1 * NPIX + pix0);
  float4 c2 = *(const float4*)(p + 2 * NPIX + pix0);
  float4 c3 = *(const float4*)(p + 3 * NPIX + pix0);
  float4 c4 = *(const float4*)(p + 4 * NPIX + pix0);
  float4 c5 = *(const float4*)(p + 5 * NPIX + pix0);
  float4 c6 = *(const float4*)(p + 6 * NPIX + pix0);
  float4 c7 = *(const float4*)(p + 7 * NPIX + pix0);
  float4 c8 = *(const float4*)(p + 8 * NPIX + pix0);

  float t = 0.f, own = 0.f;
  float e0a, e1a, e0b, e1b, e0c, e1c, e0d, e1d;
  int pa, pb2, pc, pd;
  px_work(img, x0 + 0, y, rowoff, l4.x, i4.x, c0.x, c1.x, c2.x, c3.x, c4.x, c5.x, c6.x, c7.x, c8.x, ws, ssig0, ssig1, srow, t, own, e0a, e1a, pa);
  px_work(img, x0 + 1, y, rowoff, l4.y, i4.y, c0.y, c1.y, c2.y, c3.y, c4.y, c5.y, c6.y, c7.y, c8.y, ws, ssig0, ssig1, srow, t, own, e0b, e1b, pb2);
  px_work(img, x0 + 2, y, rowoff, l4.z, i4.z, c0.z, c1.z, c2.z, c3.z, c4.z, c5.z, c6.z, c7.z, c8.z, ws, ssig0, ssig1, srow, t, own, e0c, e1c, pc);
  px_work(img, x0 + 3, y, rowoff, l4.w, i4.w, c0.w, c1.w, c2.w, c3.w, c4.w, c5.w, c6.w, c7.w, c8.w, ws, ssig0, ssig1, srow, t, own, e0d, e1d, pd);

  float* eb = (float*)ws->emb[img] + 2 * pix0;
  *(float4*)(eb) = make_float4(e0a, e1a, e0b, e1b);
  *(float4*)(eb + 4) = make_float4(e0c, e1c, e0d, e1d);
  uchar4 pv;
  pv.x = (unsigned char)(pa >= 0 ? pa : 255);
  pv.y = (unsigned char)(pb2 >= 0 ? pb2 : 255);
  pv.z = (unsigned char)(pc >= 0 ? pc : 255);
  pv.w = (unsigned char)(pd >= 0 ? pd : 255);
  *(uchar4*)(ws->pridx[img] + pix0) = pv;

  // seed scalars: wave reduce -> LDS -> one global atomic per block
  for (int o = 32; o; o >>= 1) { t += __shfl_down(t, o); own += __shfl_down(own, o); }
  if ((tid & 63) == 0) { atomicAdd(&sT, t); atomicAdd(&sO, own); }
  __syncthreads();
  if (tid == 0) {
    atomicAdd(&ws->seedT[img], sT);
    atomicAdd(&ws->seedOwn[img], sO);
  }
  if (tid < PAIRS) {
    float v0 = ssig0[tid], v1 = ssig1[tid];
    if (v0 != 0.f) atomicAdd(&ws->sigsum0[img][tid], v0);
    if (v1 != 0.f) atomicAdd(&ws->sigsum1[img][tid], v1);
  }
  if (tid < 3 * PAIRS) {
    unsigned int v = srow[tid];
    if (v) {
      int rl = tid / PAIRS, pr = tid % PAIRS;
      int yy = ybase + rl;
      if (yy < HH) atomicAdd(&ws->rowhist[img][pr][yy], v);
    }
  }
}

// ---------------- pass 2: medians from histograms (block-parallel scan), sigma means, cnt
__global__ __launch_bounds__(256) void k_medoid(WS* __restrict__ ws) {
  int img = blockIdx.x / PAIRS, p = blockIdx.x % PAIRS;
  __shared__ unsigned int pref[256];
  __shared__ int cross;
  unsigned int c = 0;
  int res[2];
#pragma unroll
  for (int h = 0; h < 2; h++) {
    const unsigned int* hist = h ? ws->rowhist[img][p] : ws->colhist[img][p];
    unsigned int v0 = hist[threadIdx.x * 3 + 0];
    unsigned int v1 = hist[threadIdx.x * 3 + 1];
    unsigned int v2 = hist[threadIdx.x * 3 + 2];
    unsigned int s = v0 + v1 + v2;
    pref[threadIdx.x] = s;
    __syncthreads();
    for (int d = 1; d < 256; d <<= 1) {
      unsigned int tv = (threadIdx.x >= d) ? pref[threadIdx.x - d] : 0u;
      __syncthreads();
      pref[threadIdx.x] += tv;
      __syncthreads();
    }
    c = pref[255];                                  // total = cnt (same for h=0,1)
    unsigned int target = (c > 0) ? (((c - 1u) >> 1) + 1u) : 1u;
    if (threadIdx.x == 0) cross = 0;
    __syncthreads();
    unsigned int inc = pref[threadIdx.x];
    unsigned int exc = inc - s;
    if (inc >= target && exc < target) {
      int j = (exc + v0 >= target) ? 0 : ((exc + v0 + v1 >= target) ? 1 : 2);
      cross = threadIdx.x * 3 + j;
    }
    __syncthreads();
    res[h] = cross;
    __syncthreads();
  }
  if (threadIdx.x == 0) {
    float vf = (c > 0) ? 1.f : 0.f;
    float cf = (c > 0) ? (float)c : 1.f;
    float sm0 = ws->sigsum0[img][p] / cf;
    float sm1 = ws->sigsum1[img][p] / cf;
    ws->cnt[img][p] = c;
    ws->medx[img][p] = basef(res[0]);
    ws->medy[img][p] = basef(res[1]);
    ws->sm0a[img][p] = sm0;
    ws->sm1a[img][p] = sm1;
    ws->s0a[img][p] = __expf(10.f * sm0);
    ws->s1a[img][p] = __expf(10.f * sm1);
    ws->validf[img][p] = vf;
    ws->cntf[img][p] = cf;
  }
}

// ---------------- pass 3: medoid argmin (first-index tie-break via 64-bit key)
// 1024 px per block (4 px/thread), 1152 blocks.
__global__ __launch_bounds__(256) void k_argmin(WS* __restrict__ ws) {
  int img = blockIdx.y;
  __shared__ unsigned long long skey[PAIRS];
  if (threadIdx.x < PAIRS) skey[threadIdx.x] = ~0ULL;
  __syncthreads();
  int px0 = blockIdx.x * 1024 + threadIdx.x * 4;
  uchar4 pr4 = *(const uchar4*)(ws->pridx[img] + px0);
  int y = px0 / WW;
  int x0 = px0 - y * WW;
  float by = basef(y);
#pragma unroll
  for (int k = 0; k < 4; k++) {
    int pr = (k == 0) ? pr4.x : (k == 1) ? pr4.y : (k == 2) ? pr4.z : pr4.w;
    if (pr != 255) {
      int pix = px0 + k;
      float dx = basef(x0 + k) - ws->medx[img][pr];
      float dy = by - ws->medy[img][pr];
      float d = dx * dx + dy * dy;
      unsigned long long key = ((unsigned long long)__float_as_uint(d) << 32) | (unsigned int)pix;
      atomicMin(&skey[pr], key);
    }
  }
  __syncthreads();
  if (threadIdx.x < PAIRS && skey[threadIdx.x] != ~0ULL)
    atomicMin(&ws->argkey[img][threadIdx.x], skey[threadIdx.x]);
}

// ---------------- pass 4 (heavy): per-(img,pair) dist map -> error histograms; fused var/seed_in
__device__ __forceinline__ void do_px(int pix, float ex, float ey, int prx,
    int p, float cx, float cy, float S0, float S1, float m0, float m1,
    const float* __restrict__ pb, int ci,
    unsigned int* hin_s, unsigned int* hout_s,
    float& vpart, float& spart) {
  float dx = ex - cx, dy = ey - cy;
  float q = dx * dx * S0 + dy * dy * S1;
  float d = __expf(-q);
  bool m = (prx == p);
  float e = m ? (2.f - 2.f * d) : (2.f * d);
  int bin = (int)(e * (BINS * 0.5f));
  bin = bin > (BINS - 1) ? (BINS - 1) : (bin < 0 ? 0 : bin);
  if (m) {
    atomicAdd(&hin_s[bin], 1u);
    float g0 = pb[2 * NPIX + pix] - m0;
    float g1 = pb[3 * NPIX + pix] - m1;
    vpart += g0 * g0 + g1 * g1;
    float sd = fast_sigmoid(pb[(4 + ci) * NPIX + pix]) - d;
    spart += sd * sd;
  } else {
    atomicAdd(&hout_s[bin], 1u);
  }
}

__global__ __launch_bounds__(256, 8) void k_hist(const float* __restrict__ pred,
                                                 WS* __restrict__ ws) {
  int chunk = blockIdx.x;    // 0..NB5-1
  int p = blockIdx.y;        // 0..PAIRS-1
  int img = blockIdx.z;      // 0..NIMG-1
  if (ws->cnt[img][p] == 0) return;   // uniform across block

  __shared__ unsigned int hin_s[BINS];
  __shared__ unsigned int hout_s[BINS];
  for (int k = threadIdx.x; k < BINS; k += 256) { hin_s[k] = 0; hout_s[k] = 0; }
  __syncthreads();

  unsigned long long key = ws->argkey[img][p];
  int imin = (int)(key & 0xffffffffu);
  float cx = basef(imin % WW);
  float cy = basef(imin / WW);
  float S0 = ws->s0a[img][p], S1 = ws->s1a[img][p];
  float m0 = ws->sm0a[img][p], m1 = ws->sm1a[img][p];
  int ci = p / MAXID;
  const float* pb = pred + (size_t)img * NCH * NPIX;
  const float* embb = (const float*)ws->emb[img];
  const unsigned char* prb = ws->pridx[img];

  float vpart = 0.f, spart = 0.f;
  int base = chunk * PXB;
#pragma unroll 2
  for (int j = 0; j < PXB / 1024; j++) {     // 8 iters, 4 px each
    int px0 = base + j * 1024 + threadIdx.x * 4;
    float4 eA = *(const float4*)(embb + 2 * px0);       // px0, px1
    float4 eB = *(const float4*)(embb + 2 * px0 + 4);   // px2, px3
    uchar4 pr4 = *(const uchar4*)(prb + px0);
    do_px(px0 + 0, eA.x, eA.y, pr4.x, p, cx, cy, S0, S1, m0, m1, pb, ci, hin_s, hout_s, vpart, spart);
    do_px(px0 + 1, eA.z, eA.w, pr4.y, p, cx, cy, S0, S1, m0, m1, pb, ci, hin_s, hout_s, vpart, spart);
    do_px(px0 + 2, eB.x, eB.y, pr4.z, p, cx, cy, S0, S1, m0, m1, pb, ci, hin_s, hout_s, vpart, spart);
    do_px(px0 + 3, eB.z, eB.w, pr4.w, p, cx, cy, S0, S1, m0, m1, pb, ci, hin_s, hout_s, vpart, spart);
  }
  __syncthreads();
  // packed u64 flush: two u32 bins per atomic; skip zeros
  for (int k = threadIdx.x * 2; k < BINS; k += 512) {
    unsigned long long vi = (unsigned long long)hin_s[k] |
                            ((unsigned long long)hin_s[k + 1] << 32);
    if (vi) atomicAdd((unsigned long long*)&ws->hin[img][p][k], vi);
    unsigned long long vo = (unsigned long long)hout_s[k] |
                            ((unsigned long long)hout_s[k + 1] << 32);
    if (vo) atomicAdd((unsigned long long*)&ws->hout[img][p][k], vo);
  }
  for (int o = 32; o; o >>= 1) { vpart += __shfl_down(vpart, o); spart += __shfl_down(spart, o); }
  __shared__ float sv, ss;
  if (threadIdx.x == 0) { sv = 0.f; ss = 0.f; }
  __syncthreads();
  if ((threadIdx.x & 63) == 0) { atomicAdd(&sv, vpart); atomicAdd(&ss, spart); }
  __syncthreads();
  if (threadIdx.x == 0) {
    atomicAdd(&ws->varsum[img][p], sv);
    atomicAdd(&ws->seedin[img][p], ss);
  }
}

// ---------------- pass 5: lovasz + (last block) final combine
__global__ __launch_bounds__(256) void k_lovasz(WS* __restrict__ ws, float* __restrict__ out) {
  int b = blockIdx.x / PAIRS, p = blockIdx.x % PAIRS;
  unsigned int gts = ws->cnt[b][p];
  float lv = 0.f;
  if (gts != 0) {
    __shared__ unsigned int tin[256], tout[256];
    unsigned int lin[8], lout[8];
    unsigned int si = 0, so = 0;
    int k0 = threadIdx.x * 8;
#pragma unroll
    for (int j = 0; j < 8; j++) {
      lin[j] = ws->hin[b][p][k0 + j];
      lout[j] = ws->hout[b][p][k0 + j];
      si += lin[j]; so += lout[j];
    }
    tin[threadIdx.x] = si; tout[threadIdx.x] = so;
    __syncthreads();
    if (threadIdx.x == 0) {   // exclusive suffix scan of per-thread totals
      unsigned int ri = 0, ro = 0;
      for (int t = 255; t >= 0; t--) {
        unsigned int a = tin[t], c2 = tout[t];
        tin[t] = ri; tout[t] = ro;
        ri += a; ro += c2;
      }
    }
    __syncthreads();
    unsigned int Sin = tin[threadIdx.x], Sout = tout[threadIdx.x];
    float gtsf = (float)gts;
    float js = 0.f;
#pragma unroll
    for (int j = 7; j >= 0; j--) {
      Sin += lin[j]; Sout += lout[j];
      int k = k0 + j;
      if (k >= 1) {
        float jac = 1.f - (float)(gts - Sin) / (gtsf + (float)Sout);
        js += jac;
      }
    }
    for (int o = 32; o; o >>= 1) js += __shfl_down(js, o);
    __shared__ float wsum[4];
    if ((threadIdx.x & 63) == 0) wsum[threadIdx.x >> 6] = js;
    __syncthreads();
    if (threadIdx.x == 0)
      lv = (2.f / BINS) * (0.5f + wsum[0] + wsum[1] + wsum[2] + wsum[3]);
  }
  if (threadIdx.x == 0) {
    atomicExch(&ws->lov[b][p], lv);           // device-scope publish (G16)
    __threadfence();
    unsigned int old = atomicAdd(&ws->lovdone, 1u);
    if (old == NIMG * PAIRS - 1) {            // last block: final combine
      float tot = 0.f;
      for (int bb = 0; bb < NIMG; bb++) {
        float lovs = 0.f, vars = 0.f, sins = 0.f, objs = 0.f;
        for (int pp = 0; pp < PAIRS; pp++) {
          float vf = ws->validf[bb][pp];      // prev-kernel data: plain loads OK
          objs += vf;
          lovs += vf * atomicAdd(&ws->lov[bb][pp], 0.f);  // same-kernel: atomic read
          vars += vf * ws->varsum[bb][pp] / (ws->cntf[bb][pp] * 2.f);  // /(cnts*NS)
          sins += vf * ws->seedin[bb][pp];                             // class_weight = 1
        }
        if (objs < 1.f) objs = 1.f;
        float seed_bg = ws->seedT[bb] - ws->seedOwn[bb];
        float seed_loss = (seed_bg + sins) / (float)NPIX;
        tot += lovs / objs + 10.f * vars / objs + seed_loss;
      }
      out[0] = tot * 0.5f;
    }
  }
}

extern "C" void kernel_launch(void* const* d_in, const int* in_sizes, int n_in,
                              void* d_out, int out_size, void* d_ws, size_t ws_size,
                              hipStream_t stream) {
  const float* pred = (const float*)d_in[0];
  const int* inst = (const int*)d_in[1];
  const int* lab = (const int*)d_in[2];
  WS* ws = (WS*)d_ws;

  size_t zoff = offsetof(WS, cnt);
  size_t zend = offsetof(WS, emb);
  hipMemsetAsync((char*)d_ws, 0xFF, zoff, stream);                 // argmin keys -> u64 max
  hipMemsetAsync((char*)d_ws + zoff, 0, zend - zoff, stream);      // accumulators -> 0

  k_pass1<<<dim3(NPIX / 1024, NIMG), 256, 0, stream>>>(pred, inst, lab, ws);
  k_medoid<<<dim3(NIMG * PAIRS), 256, 0, stream>>>(ws);
  k_argmin<<<dim3(NPIX / 1024, NIMG), 256, 0, stream>>>(ws);
  k_hist<<<dim3(NB5, PAIRS, NIMG), 256, 0, stream>>>(pred, ws);
  k_lovasz<<<dim3(NIMG * PAIRS), 256, 0, stream>>>(ws, (float*)d_out);
}

// Round 5
// 121.835 us; speedup vs baseline: 1.4631x; 1.4631x over previous
//
#include <hip/hip_runtime.h>
#include <cstddef>
#include <cstdint>

// SpatialEmbLoss on MI355X.
// H=W=768, 2 images, NC=5 classes, MAX_ID=3 -> 15 (class,id) pairs per image.
// Lovasz hinge via 2048-bin error histogram:
//   lov = integral_0^2 jac(t) dt,  jac(t) = 1 - (gts - n_in(t))/(gts + n_out(t))
// Round 5: (1) k_pass1 atomic-free -- 64x24 tiles, LDS col/row hists, plain u16
// partial stores (r4 had ~23MB atomic writeback + 576-deep flush chains);
// k_medoid reduces partials. (2) k_hist single-round grid (1920 blocks = 8/CU).
// (3) last-lovasz-block final combine uses 30 CONCURRENT atomic reads (r4 had
// 30 sequential dependent ones).

#define HH 768
#define WW 768
#define NPIX (HH*WW)            // 589824
#define NCL 5
#define MAXID 3
#define PAIRS (NCL*MAXID)       // 15
#define NIMG 2
#define NCH 9                   // 2 emb + 2 sigma + 5 seed channels
#define BINS 2048
#define PXB 9216                // pixels per k_hist block (36/thread)
#define NB5 (NPIX/PXB)          // 64 chunks -> 64*15*2 = 1920 blocks (one round)
#define TX 12                   // x-tiles (64 cols each)
#define TY 32                   // y-tiles (24 rows each)
#define XW 64
#define YH 24
#define BPI (TX*TY)             // 384 pass1 blocks per image

struct P1 {                      // per-pass1-block partials (2768 B)
  unsigned short col[PAIRS][XW];
  unsigned short row[PAIRS][YH];
  float sig0[PAIRS], sig1[PAIRS];
  float sT, sO;
};

struct WS {
  unsigned long long argkey[NIMG][PAIRS];   // init 0xFF (atomicMin keys)
  // ---------- zero region ----------
  unsigned int cnt[NIMG][PAIRS];
  unsigned int lovdone;
  unsigned int pad0;
  alignas(8) unsigned int hin[NIMG][PAIRS][BINS];
  alignas(8) unsigned int hout[NIMG][PAIRS][BINS];
  float varsum[NIMG][PAIRS];
  float seedin[NIMG][PAIRS];
  // ---------- end zero region ----------
  float medx[NIMG][PAIRS], medy[NIMG][PAIRS];
  float s0a[NIMG][PAIRS], s1a[NIMG][PAIRS];
  float sm0a[NIMG][PAIRS], sm1a[NIMG][PAIRS];
  float validf[NIMG][PAIRS], cntf[NIMG][PAIRS];
  float lov[NIMG][PAIRS];
  float seedT[NIMG], seedOwn[NIMG];
  alignas(16) float2 emb[NIMG][NPIX];      // {tanh(p0)+x, tanh(p1)+y}
  unsigned char pridx[NIMG][NPIX];         // pair index 0..14, 255 = none
  alignas(4) P1 part[NIMG][BPI];           // pass1 partials (atomic-free)
};

__device__ __forceinline__ float basef(int i) {
  // jnp.linspace(0,1,1024)[i]
  return (float)i * (1.0f / 1023.0f);
}
__device__ __forceinline__ int pair_of(int l, int it) {
  return (l >= 1 && l <= NCL && it >= 1 && it <= MAXID) ? (l - 1) * MAXID + (it - 1) : -1;
}
__device__ __forceinline__ float fast_sigmoid(float z) {
  return __fdividef(1.f, 1.f + __expf(-z));
}
__device__ __forceinline__ float fast_tanh(float x) {
  float xc = fminf(fmaxf(x, -15.f), 15.f);
  float e = __expf(2.f * xc);
  return __fdividef(e - 1.f, e + 1.f);
}

// ---------------- pass 1: tile 64x24; LDS hists; plain partial stores (NO global atomics)
__global__ __launch_bounds__(256) void k_pass1(const float* __restrict__ pred,
                                               const int* __restrict__ inst,
                                               const int* __restrict__ lab,
                                               WS* __restrict__ ws) {
  int img = blockIdx.z;
  int x0 = blockIdx.x * XW;
  int y0 = blockIdx.y * YH;
  int tid = threadIdx.x, lane = tid & 63, wv = tid >> 6;
  const float* p = pred + (size_t)img * NCH * NPIX;
  const int* lb = lab + (size_t)img * NPIX;
  const int* ib = inst + (size_t)img * NPIX;

  __shared__ unsigned int lcol[PAIRS][XW];   // bank = lane&31 -> 2-way, free
  __shared__ unsigned int lrow[PAIRS][YH];
  __shared__ float lsig0[PAIRS], lsig1[PAIRS];
  __shared__ float fred0[4], fred1[4];
  for (int k = tid; k < PAIRS * XW; k += 256) ((unsigned int*)lcol)[k] = 0;
  for (int k = tid; k < PAIRS * YH; k += 256) ((unsigned int*)lrow)[k] = 0;
  if (tid < PAIRS) { lsig0[tid] = 0.f; lsig1[tid] = 0.f; }
  __syncthreads();

  int x = x0 + lane;
  float bx = basef(x);
  float t = 0.f, own = 0.f;
#pragma unroll
  for (int i = 0; i < YH / 4; i++) {         // 6 rows per wave
    int y = y0 + wv + 4 * i;
    int pix = y * WW + x;
    int l = lb[pix];
    int it = ib[pix];
    float s, q;
    s = fast_sigmoid(p[4 * NPIX + pix]); q = s * s; t += q; if (l == 1) own += q;
    s = fast_sigmoid(p[5 * NPIX + pix]); q = s * s; t += q; if (l == 2) own += q;
    s = fast_sigmoid(p[6 * NPIX + pix]); q = s * s; t += q; if (l == 3) own += q;
    s = fast_sigmoid(p[7 * NPIX + pix]); q = s * s; t += q; if (l == 4) own += q;
    s = fast_sigmoid(p[8 * NPIX + pix]); q = s * s; t += q; if (l == 5) own += q;
    float e0 = fast_tanh(p[0 * NPIX + pix]) + bx;
    float e1 = fast_tanh(p[1 * NPIX + pix]) + basef(y);
    ws->emb[img][pix] = make_float2(e0, e1);
    int pr = pair_of(l, it);
    ws->pridx[img][pix] = (unsigned char)(pr >= 0 ? pr : 255);
    if (pr >= 0) {
      atomicAdd(&lcol[pr][lane], 1u);
      atomicAdd(&lrow[pr][y - y0], 1u);
      atomicAdd(&lsig0[pr], p[2 * NPIX + pix]);
      atomicAdd(&lsig1[pr], p[3 * NPIX + pix]);
    }
  }
  // seed scalars: wave reduce -> LDS
  for (int o = 32; o; o >>= 1) { t += __shfl_down(t, o); own += __shfl_down(own, o); }
  if (lane == 0) { fred0[wv] = t; fred1[wv] = own; }
  __syncthreads();

  // flush partials (plain stores, coalesced-ish)
  P1* P = &ws->part[img][blockIdx.x * TY + blockIdx.y];
  const unsigned int* fc = (const unsigned int*)lcol;
  for (int k = tid; k < PAIRS * XW / 2; k += 256) {   // 480 u32 (u16 pairs)
    unsigned int lo = fc[2 * k], hi = fc[2 * k + 1];
    ((unsigned int*)P->col)[k] = (lo & 0xFFFFu) | (hi << 16);
  }
  const unsigned int* fr = (const unsigned int*)lrow;
  for (int k = tid; k < PAIRS * YH / 2; k += 256) {   // 180 u32
    unsigned int lo = fr[2 * k], hi = fr[2 * k + 1];
    ((unsigned int*)P->row)[k] = (lo & 0xFFFFu) | (hi << 16);
  }
  if (tid < PAIRS) { P->sig0[tid] = lsig0[tid]; P->sig1[tid] = lsig1[tid]; }
  if (tid == 0) {
    P->sT = fred0[0] + fred0[1] + fred0[2] + fred0[3];
    P->sO = fred1[0] + fred1[1] + fred1[2] + fred1[3];
  }
}

// ---------------- pass 2: reduce partials + medians (block scan) + sigma means + cnt
__global__ __launch_bounds__(256) void k_medoid(WS* __restrict__ ws) {
  int img = blockIdx.x / PAIRS, p = blockIdx.x % PAIRS;
  const P1* B = ws->part[img];
  int tid = threadIdx.x, lane = tid & 63, wv = tid >> 6;
  __shared__ unsigned int pref[256];
  __shared__ int cross;
  __shared__ float fr0[4], fr1[4];
  unsigned int c = 0;
  int res[2];
#pragma unroll
  for (int h = 0; h < 2; h++) {
    unsigned int v[3];
#pragma unroll
    for (int j = 0; j < 3; j++) {
      int cc = tid * 3 + j;      // col or row index 0..767
      unsigned int s = 0;
      if (h == 0) {
        int xt = cc >> 6, ci = cc & 63;
        for (int yt = 0; yt < TY; yt++) s += B[xt * TY + yt].col[p][ci];
      } else {
        int yt = cc / YH, ri = cc % YH;
        for (int xt = 0; xt < TX; xt++) s += B[xt * TY + yt].row[p][ri];
      }
      v[j] = s;
    }
    unsigned int s3 = v[0] + v[1] + v[2];
    pref[tid] = s3;
    __syncthreads();
    for (int d = 1; d < 256; d <<= 1) {
      unsigned int tv = (tid >= d) ? pref[tid - d] : 0u;
      __syncthreads();
      pref[tid] += tv;
      __syncthreads();
    }
    c = pref[255];
    unsigned int target = (c > 0) ? (((c - 1u) >> 1) + 1u) : 1u;
    if (tid == 0) cross = 0;
    __syncthreads();
    unsigned int inc = pref[tid];
    unsigned int exc = inc - s3;
    if (inc >= target && exc < target) {
      int j = (exc + v[0] >= target) ? 0 : ((exc + v[0] + v[1] >= target) ? 1 : 2);
      cross = tid * 3 + j;
    }
    __syncthreads();
    res[h] = cross;
    __syncthreads();
  }
  // sigma sums over 384 partials
  float s0 = 0.f, s1 = 0.f;
  for (int b = tid; b < BPI; b += 256) { s0 += B[b].sig0[p]; s1 += B[b].sig1[p]; }
  for (int o = 32; o; o >>= 1) { s0 += __shfl_down(s0, o); s1 += __shfl_down(s1, o); }
  if (lane == 0) { fr0[wv] = s0; fr1[wv] = s1; }
  __syncthreads();
  if (tid == 0) {
    float sig0 = fr0[0] + fr0[1] + fr0[2] + fr0[3];
    float sig1 = fr1[0] + fr1[1] + fr1[2] + fr1[3];
    float vf = (c > 0) ? 1.f : 0.f;
    float cf = (c > 0) ? (float)c : 1.f;
    float sm0 = sig0 / cf, sm1 = sig1 / cf;
    ws->cnt[img][p] = c;
    ws->medx[img][p] = basef(res[0]);
    ws->medy[img][p] = basef(res[1]);
    ws->sm0a[img][p] = sm0;
    ws->sm1a[img][p] = sm1;
    ws->s0a[img][p] = __expf(10.f * sm0);
    ws->s1a[img][p] = __expf(10.f * sm1);
    ws->validf[img][p] = vf;
    ws->cntf[img][p] = cf;
  }
  __syncthreads();
  if (p == 0) {      // seed totals, once per image
    float a = 0.f, o2 = 0.f;
    for (int b = tid; b < BPI; b += 256) { a += B[b].sT; o2 += B[b].sO; }
    for (int o = 32; o; o >>= 1) { a += __shfl_down(a, o); o2 += __shfl_down(o2, o); }
    if (lane == 0) { fr0[wv] = a; fr1[wv] = o2; }
    __syncthreads();
    if (tid == 0) {
      ws->seedT[img] = fr0[0] + fr0[1] + fr0[2] + fr0[3];
      ws->seedOwn[img] = fr1[0] + fr1[1] + fr1[2] + fr1[3];
    }
  }
}

// ---------------- pass 3: medoid argmin (first-index tie-break via 64-bit key)
__global__ __launch_bounds__(256) void k_argmin(WS* __restrict__ ws) {
  int img = blockIdx.y;
  __shared__ unsigned long long skey[PAIRS];
  __shared__ float smx[PAIRS], smy[PAIRS];
  if (threadIdx.x < PAIRS) {
    skey[threadIdx.x] = ~0ULL;
    smx[threadIdx.x] = ws->medx[img][threadIdx.x];
    smy[threadIdx.x] = ws->medy[img][threadIdx.x];
  }
  __syncthreads();
  int px0 = blockIdx.x * 1024 + threadIdx.x * 4;
  uchar4 pr4 = *(const uchar4*)(ws->pridx[img] + px0);
  int y = px0 / WW;
  int x0 = px0 - y * WW;
  float by = basef(y);
#pragma unroll
  for (int k = 0; k < 4; k++) {
    int pr = (k == 0) ? pr4.x : (k == 1) ? pr4.y : (k == 2) ? pr4.z : pr4.w;
    if (pr != 255) {
      int pix = px0 + k;
      float dx = basef(x0 + k) - smx[pr];
      float dy = by - smy[pr];
      float d = dx * dx + dy * dy;
      unsigned long long key = ((unsigned long long)__float_as_uint(d) << 32) | (unsigned int)pix;
      atomicMin(&skey[pr], key);
    }
  }
  __syncthreads();
  if (threadIdx.x < PAIRS && skey[threadIdx.x] != ~0ULL)
    atomicMin(&ws->argkey[img][threadIdx.x], skey[threadIdx.x]);
}

// ---------------- pass 4 (heavy): per-(img,pair) dist map -> error histograms; fused var/seed_in
__device__ __forceinline__ void do_px(int pix, float ex, float ey, int prx,
    int p, float cx, float cy, float S0, float S1, float m0, float m1,
    const float* __restrict__ pb, int ci,
    unsigned int* hin_s, unsigned int* hout_s,
    float& vpart, float& spart) {
  float dx = ex - cx, dy = ey - cy;
  float q = dx * dx * S0 + dy * dy * S1;
  float d = __expf(-q);
  bool m = (prx == p);
  float e = m ? (2.f - 2.f * d) : (2.f * d);
  int bin = (int)(e * (BINS * 0.5f));
  bin = bin > (BINS - 1) ? (BINS - 1) : (bin < 0 ? 0 : bin);
  if (m) {
    atomicAdd(&hin_s[bin], 1u);
    float g0 = pb[2 * NPIX + pix] - m0;
    float g1 = pb[3 * NPIX + pix] - m1;
    vpart += g0 * g0 + g1 * g1;
    float sd = fast_sigmoid(pb[(4 + ci) * NPIX + pix]) - d;
    spart += sd * sd;
  } else {
    atomicAdd(&hout_s[bin], 1u);
  }
}

__global__ __launch_bounds__(256, 8) void k_hist(const float* __restrict__ pred,
                                                 WS* __restrict__ ws) {
  int chunk = blockIdx.x;    // 0..NB5-1
  int p = blockIdx.y;        // 0..PAIRS-1
  int img = blockIdx.z;      // 0..NIMG-1
  if (ws->cnt[img][p] == 0) return;   // uniform across block

  __shared__ unsigned int hin_s[BINS];
  __shared__ unsigned int hout_s[BINS];
  for (int k = threadIdx.x; k < BINS; k += 256) { hin_s[k] = 0; hout_s[k] = 0; }
  __syncthreads();

  unsigned long long key = ws->argkey[img][p];
  int imin = (int)(key & 0xffffffffu);
  float cx = basef(imin % WW);
  float cy = basef(imin / WW);
  float S0 = ws->s0a[img][p], S1 = ws->s1a[img][p];
  float m0 = ws->sm0a[img][p], m1 = ws->sm1a[img][p];
  int ci = p / MAXID;
  const float* pb = pred + (size_t)img * NCH * NPIX;
  const float* embb = (const float*)ws->emb[img];
  const unsigned char* prb = ws->pridx[img];

  float vpart = 0.f, spart = 0.f;
  int base = chunk * PXB;
#pragma unroll 3
  for (int j = 0; j < PXB / 1024; j++) {     // 9 iters, 4 px each
    int px0 = base + j * 1024 + threadIdx.x * 4;
    float4 eA = *(const float4*)(embb + 2 * px0);       // px0, px1
    float4 eB = *(const float4*)(embb + 2 * px0 + 4);   // px2, px3
    uchar4 pr4 = *(const uchar4*)(prb + px0);
    do_px(px0 + 0, eA.x, eA.y, pr4.x, p, cx, cy, S0, S1, m0, m1, pb, ci, hin_s, hout_s, vpart, spart);
    do_px(px0 + 1, eA.z, eA.w, pr4.y, p, cx, cy, S0, S1, m0, m1, pb, ci, hin_s, hout_s, vpart, spart);
    do_px(px0 + 2, eB.x, eB.y, pr4.z, p, cx, cy, S0, S1, m0, m1, pb, ci, hin_s, hout_s, vpart, spart);
    do_px(px0 + 3, eB.z, eB.w, pr4.w, p, cx, cy, S0, S1, m0, m1, pb, ci, hin_s, hout_s, vpart, spart);
  }
  __syncthreads();
  // packed u64 flush: two u32 bins per atomic; skip zeros
  for (int k = threadIdx.x * 2; k < BINS; k += 512) {
    unsigned long long vi = (unsigned long long)hin_s[k] |
                            ((unsigned long long)hin_s[k + 1] << 32);
    if (vi) atomicAdd((unsigned long long*)&ws->hin[img][p][k], vi);
    unsigned long long vo = (unsigned long long)hout_s[k] |
                            ((unsigned long long)hout_s[k + 1] << 32);
    if (vo) atomicAdd((unsigned long long*)&ws->hout[img][p][k], vo);
  }
  for (int o = 32; o; o >>= 1) { vpart += __shfl_down(vpart, o); spart += __shfl_down(spart, o); }
  __shared__ float sv, ss;
  if (threadIdx.x == 0) { sv = 0.f; ss = 0.f; }
  __syncthreads();
  if ((threadIdx.x & 63) == 0) { atomicAdd(&sv, vpart); atomicAdd(&ss, spart); }
  __syncthreads();
  if (threadIdx.x == 0) {
    atomicAdd(&ws->varsum[img][p], sv);
    atomicAdd(&ws->seedin[img][p], ss);
  }
}

// ---------------- pass 5: lovasz + (last block) final combine
__global__ __launch_bounds__(256) void k_lovasz(WS* __restrict__ ws, float* __restrict__ out) {
  int b = blockIdx.x / PAIRS, p = blockIdx.x % PAIRS;
  unsigned int gts = ws->cnt[b][p];
  float lv = 0.f;
  int tid = threadIdx.x;
  if (gts != 0) {
    __shared__ unsigned int tin[256], tout[256];
    unsigned int lin[8], lout[8];
    unsigned int si = 0, so = 0;
    int k0 = tid * 8;
#pragma unroll
    for (int j = 0; j < 8; j++) {
      lin[j] = ws->hin[b][p][k0 + j];
      lout[j] = ws->hout[b][p][k0 + j];
      si += lin[j]; so += lout[j];
    }
    tin[tid] = si; tout[tid] = so;
    __syncthreads();
    if (tid == 0) {   // exclusive suffix scan of per-thread totals
      unsigned int ri = 0, ro = 0;
      for (int t = 255; t >= 0; t--) {
        unsigned int a = tin[t], c2 = tout[t];
        tin[t] = ri; tout[t] = ro;
        ri += a; ro += c2;
      }
    }
    __syncthreads();
    unsigned int Sin = tin[tid], Sout = tout[tid];
    float gtsf = (float)gts;
    float js = 0.f;
#pragma unroll
    for (int j = 7; j >= 0; j--) {
      Sin += lin[j]; Sout += lout[j];
      int k = k0 + j;
      if (k >= 1) {
        float jac = 1.f - (float)(gts - Sin) / (gtsf + (float)Sout);
        js += jac;
      }
    }
    for (int o = 32; o; o >>= 1) js += __shfl_down(js, o);
    __shared__ float wsum[4];
    if ((tid & 63) == 0) wsum[tid >> 6] = js;
    __syncthreads();
    if (tid == 0)
      lv = (2.f / BINS) * (0.5f + wsum[0] + wsum[1] + wsum[2] + wsum[3]);
  }
  __shared__ int amLast;
  if (tid == 0) {
    atomicExch(&ws->lov[b][p], lv);           // device-scope publish (G16)
    __threadfence();
    unsigned int old = atomicAdd(&ws->lovdone, 1u);
    amLast = (old == NIMG * PAIRS - 1);
  }
  __syncthreads();
  if (amLast) {
    __shared__ float rl[NIMG], rv[NIMG], rs[NIMG], ro[NIMG];
    if (tid < NIMG) { rl[tid] = 0.f; rv[tid] = 0.f; rs[tid] = 0.f; ro[tid] = 0.f; }
    __syncthreads();
    if (tid < NIMG * PAIRS) {                 // 30 CONCURRENT atomic reads
      int bb = tid / PAIRS, pp = tid % PAIRS;
      float vf = ws->validf[bb][pp];
      float lvv = atomicAdd(&ws->lov[bb][pp], 0.f);  // same-kernel cross-XCD read
      atomicAdd(&rl[bb], vf * lvv);
      atomicAdd(&rv[bb], vf * ws->varsum[bb][pp] / (ws->cntf[bb][pp] * 2.f));
      atomicAdd(&rs[bb], vf * ws->seedin[bb][pp]);
      atomicAdd(&ro[bb], vf);
    }
    __syncthreads();
    if (tid == 0) {
      float tot = 0.f;
      for (int bb = 0; bb < NIMG; bb++) {
        float objs = ro[bb] < 1.f ? 1.f : ro[bb];
        float seed_bg = ws->seedT[bb] - ws->seedOwn[bb];
        float seed_loss = (seed_bg + rs[bb]) / (float)NPIX;
        tot += rl[bb] / objs + 10.f * rv[bb] / objs + seed_loss;
      }
      out[0] = tot * 0.5f;
    }
  }
}

extern "C" void kernel_launch(void* const* d_in, const int* in_sizes, int n_in,
                              void* d_out, int out_size, void* d_ws, size_t ws_size,
                              hipStream_t stream) {
  const float* pred = (const float*)d_in[0];
  const int* inst = (const int*)d_in[1];
  const int* lab = (const int*)d_in[2];
  WS* ws = (WS*)d_ws;

  size_t zoff = offsetof(WS, cnt);
  size_t zend = offsetof(WS, medx);
  hipMemsetAsync((char*)d_ws, 0xFF, zoff, stream);                 // argmin keys -> u64 max
  hipMemsetAsync((char*)d_ws + zoff, 0, zend - zoff, stream);      // accumulators -> 0

  k_pass1<<<dim3(TX, TY, NIMG), 256, 0, stream>>>(pred, inst, lab, ws);
  k_medoid<<<dim3(NIMG * PAIRS), 256, 0, stream>>>(ws);
  k_argmin<<<dim3(NPIX / 1024, NIMG), 256, 0, stream>>>(ws);
  k_hist<<<dim3(NB5, PAIRS, NIMG), 256, 0, stream>>>(pred, ws);
  k_lovasz<<<dim3(NIMG * PAIRS), 256, 0, stream>>>(ws, (float*)d_out);
}

// Round 6
// 95.821 us; speedup vs baseline: 1.8603x; 1.2715x over previous
//
#include <hip/hip_runtime.h>
#include <cstddef>
#include <cstdint>

// SpatialEmbLoss on MI355X.
// H=W=768, 2 images, NC=5 classes, MAX_ID=3 -> 15 (class,id) pairs per image.
// Lovasz hinge via 256-bin error histogram:
//   lov = integral_0^2 jac(t) dt,  jac(t) = 1 - (gts - n_in(t))/(gts + n_out(t))
//   (jac monotone 0->1 -> trapezoid err <= 1/256 per instance; threshold 0.26)
// Round 6: invert k_hist loop -- ONE pixel pass computing ALL 15 pairs/px
// (was: 15 passes re-streaming 160MB through L3, latency-bound at 36% VALU).
// All 30 histograms live in LDS (BINS=256 -> 30.7KB, 5 blocks/CU). Pair
// constants in registers (full unroll, compile-time indices). 15x less load
// traffic, ~200 VALU per 9B loaded.

#define HH 768
#define WW 768
#define NPIX (HH*WW)            // 589824
#define NCL 5
#define MAXID 3
#define PAIRS (NCL*MAXID)       // 15
#define NIMG 2
#define NCH 9                   // 2 emb + 2 sigma + 5 seed channels
#define BINS 256
#define HPXB 2304               // pixels per k_hist block (9/thread)
#define HNB (NPIX/HPXB)         // 256 blocks per image
#define TX 12                   // pass1 x-tiles (64 cols each)
#define TY 32                   // pass1 y-tiles (24 rows each)
#define XW 64
#define YH 24
#define BPI (TX*TY)             // 384 pass1 blocks per image

struct P1 {                      // per-pass1-block partials
  unsigned short col[PAIRS][XW];
  unsigned short row[PAIRS][YH];
  float sig0[PAIRS], sig1[PAIRS];
  float sT, sO;
};

struct WS {
  unsigned long long argkey[NIMG][PAIRS];   // init 0xFF (atomicMin keys)
  // ---------- zero region ----------
  unsigned int cnt[NIMG][PAIRS];
  unsigned int lovdone;
  unsigned int pad0;
  alignas(8) unsigned int hall[NIMG][PAIRS][2][BINS];  // [0]=out, [1]=in
  float varsum[NIMG][PAIRS];
  float seedin[NIMG][PAIRS];
  // ---------- end zero region ----------
  float medx[NIMG][PAIRS], medy[NIMG][PAIRS];
  float s0a[NIMG][PAIRS], s1a[NIMG][PAIRS];
  float sm0a[NIMG][PAIRS], sm1a[NIMG][PAIRS];
  float validf[NIMG][PAIRS], cntf[NIMG][PAIRS];
  float lov[NIMG][PAIRS];
  float seedT[NIMG], seedOwn[NIMG];
  alignas(16) float2 emb[NIMG][NPIX];      // {tanh(p0)+x, tanh(p1)+y}
  unsigned char pridx[NIMG][NPIX];         // pair index 0..14, 255 = none
  alignas(4) P1 part[NIMG][BPI];           // pass1 partials (atomic-free)
};

__device__ __forceinline__ float basef(int i) {
  // jnp.linspace(0,1,1024)[i]
  return (float)i * (1.0f / 1023.0f);
}
__device__ __forceinline__ int pair_of(int l, int it) {
  return (l >= 1 && l <= NCL && it >= 1 && it <= MAXID) ? (l - 1) * MAXID + (it - 1) : -1;
}
__device__ __forceinline__ float fast_sigmoid(float z) {
  return __fdividef(1.f, 1.f + __expf(-z));
}
__device__ __forceinline__ float fast_tanh(float x) {
  float xc = fminf(fmaxf(x, -15.f), 15.f);
  float e = __expf(2.f * xc);
  return __fdividef(e - 1.f, e + 1.f);
}

// ---------------- pass 1: tile 64x24; LDS hists; plain partial stores (NO global atomics)
__global__ __launch_bounds__(256) void k_pass1(const float* __restrict__ pred,
                                               const int* __restrict__ inst,
                                               const int* __restrict__ lab,
                                               WS* __restrict__ ws) {
  int img = blockIdx.z;
  int x0 = blockIdx.x * XW;
  int y0 = blockIdx.y * YH;
  int tid = threadIdx.x, lane = tid & 63, wv = tid >> 6;
  const float* p = pred + (size_t)img * NCH * NPIX;
  const int* lb = lab + (size_t)img * NPIX;
  const int* ib = inst + (size_t)img * NPIX;

  __shared__ unsigned int lcol[PAIRS][XW];   // bank = lane&31 -> 2-way, free
  __shared__ unsigned int lrow[PAIRS][YH];
  __shared__ float lsig0[PAIRS], lsig1[PAIRS];
  __shared__ float fred0[4], fred1[4];
  for (int k = tid; k < PAIRS * XW; k += 256) ((unsigned int*)lcol)[k] = 0;
  for (int k = tid; k < PAIRS * YH; k += 256) ((unsigned int*)lrow)[k] = 0;
  if (tid < PAIRS) { lsig0[tid] = 0.f; lsig1[tid] = 0.f; }
  __syncthreads();

  int x = x0 + lane;
  float bx = basef(x);
  float t = 0.f, own = 0.f;
#pragma unroll
  for (int i = 0; i < YH / 4; i++) {         // 6 rows per wave
    int y = y0 + wv + 4 * i;
    int pix = y * WW + x;
    int l = lb[pix];
    int it = ib[pix];
    float s, q;
    s = fast_sigmoid(p[4 * NPIX + pix]); q = s * s; t += q; if (l == 1) own += q;
    s = fast_sigmoid(p[5 * NPIX + pix]); q = s * s; t += q; if (l == 2) own += q;
    s = fast_sigmoid(p[6 * NPIX + pix]); q = s * s; t += q; if (l == 3) own += q;
    s = fast_sigmoid(p[7 * NPIX + pix]); q = s * s; t += q; if (l == 4) own += q;
    s = fast_sigmoid(p[8 * NPIX + pix]); q = s * s; t += q; if (l == 5) own += q;
    float e0 = fast_tanh(p[0 * NPIX + pix]) + bx;
    float e1 = fast_tanh(p[1 * NPIX + pix]) + basef(y);
    ws->emb[img][pix] = make_float2(e0, e1);
    int pr = pair_of(l, it);
    ws->pridx[img][pix] = (unsigned char)(pr >= 0 ? pr : 255);
    if (pr >= 0) {
      atomicAdd(&lcol[pr][lane], 1u);
      atomicAdd(&lrow[pr][y - y0], 1u);
      atomicAdd(&lsig0[pr], p[2 * NPIX + pix]);
      atomicAdd(&lsig1[pr], p[3 * NPIX + pix]);
    }
  }
  // seed scalars: wave reduce -> LDS
  for (int o = 32; o; o >>= 1) { t += __shfl_down(t, o); own += __shfl_down(own, o); }
  if (lane == 0) { fred0[wv] = t; fred1[wv] = own; }
  __syncthreads();

  // flush partials (plain stores)
  P1* P = &ws->part[img][blockIdx.x * TY + blockIdx.y];
  const unsigned int* fc = (const unsigned int*)lcol;
  for (int k = tid; k < PAIRS * XW / 2; k += 256) {   // 480 u32 (u16 pairs)
    unsigned int lo = fc[2 * k], hi = fc[2 * k + 1];
    ((unsigned int*)P->col)[k] = (lo & 0xFFFFu) | (hi << 16);
  }
  const unsigned int* fr = (const unsigned int*)lrow;
  for (int k = tid; k < PAIRS * YH / 2; k += 256) {   // 180 u32
    unsigned int lo = fr[2 * k], hi = fr[2 * k + 1];
    ((unsigned int*)P->row)[k] = (lo & 0xFFFFu) | (hi << 16);
  }
  if (tid < PAIRS) { P->sig0[tid] = lsig0[tid]; P->sig1[tid] = lsig1[tid]; }
  if (tid == 0) {
    P->sT = fred0[0] + fred0[1] + fred0[2] + fred0[3];
    P->sO = fred1[0] + fred1[1] + fred1[2] + fred1[3];
  }
}

// ---------------- pass 2: reduce partials + medians (block scan) + sigma means + cnt
__global__ __launch_bounds__(256) void k_medoid(WS* __restrict__ ws) {
  int img = blockIdx.x / PAIRS, p = blockIdx.x % PAIRS;
  const P1* B = ws->part[img];
  int tid = threadIdx.x, lane = tid & 63, wv = tid >> 6;
  __shared__ unsigned int pref[256];
  __shared__ int cross;
  __shared__ float fr0[4], fr1[4];
  unsigned int c = 0;
  int res[2];
#pragma unroll
  for (int h = 0; h < 2; h++) {
    unsigned int v[3];
#pragma unroll
    for (int j = 0; j < 3; j++) {
      int cc = tid * 3 + j;      // col or row index 0..767
      unsigned int s = 0;
      if (h == 0) {
        int xt = cc >> 6, ci = cc & 63;
        for (int yt = 0; yt < TY; yt++) s += B[xt * TY + yt].col[p][ci];
      } else {
        int yt = cc / YH, ri = cc % YH;
        for (int xt = 0; xt < TX; xt++) s += B[xt * TY + yt].row[p][ri];
      }
      v[j] = s;
    }
    unsigned int s3 = v[0] + v[1] + v[2];
    pref[tid] = s3;
    __syncthreads();
    for (int d = 1; d < 256; d <<= 1) {
      unsigned int tv = (tid >= d) ? pref[tid - d] : 0u;
      __syncthreads();
      pref[tid] += tv;
      __syncthreads();
    }
    c = pref[255];
    unsigned int target = (c > 0) ? (((c - 1u) >> 1) + 1u) : 1u;
    if (tid == 0) cross = 0;
    __syncthreads();
    unsigned int inc = pref[tid];
    unsigned int exc = inc - s3;
    if (inc >= target && exc < target) {
      int j = (exc + v[0] >= target) ? 0 : ((exc + v[0] + v[1] >= target) ? 1 : 2);
      cross = tid * 3 + j;
    }
    __syncthreads();
    res[h] = cross;
    __syncthreads();
  }
  // sigma sums over 384 partials
  float s0 = 0.f, s1 = 0.f;
  for (int b = tid; b < BPI; b += 256) { s0 += B[b].sig0[p]; s1 += B[b].sig1[p]; }
  for (int o = 32; o; o >>= 1) { s0 += __shfl_down(s0, o); s1 += __shfl_down(s1, o); }
  if (lane == 0) { fr0[wv] = s0; fr1[wv] = s1; }
  __syncthreads();
  if (tid == 0) {
    float sig0 = fr0[0] + fr0[1] + fr0[2] + fr0[3];
    float sig1 = fr1[0] + fr1[1] + fr1[2] + fr1[3];
    float vf = (c > 0) ? 1.f : 0.f;
    float cf = (c > 0) ? (float)c : 1.f;
    float sm0 = sig0 / cf, sm1 = sig1 / cf;
    ws->cnt[img][p] = c;
    ws->medx[img][p] = basef(res[0]);
    ws->medy[img][p] = basef(res[1]);
    ws->sm0a[img][p] = sm0;
    ws->sm1a[img][p] = sm1;
    ws->s0a[img][p] = __expf(10.f * sm0);
    ws->s1a[img][p] = __expf(10.f * sm1);
    ws->validf[img][p] = vf;
    ws->cntf[img][p] = cf;
  }
  __syncthreads();
  if (p == 0) {      // seed totals, once per image
    float a = 0.f, o2 = 0.f;
    for (int b = tid; b < BPI; b += 256) { a += B[b].sT; o2 += B[b].sO; }
    for (int o = 32; o; o >>= 1) { a += __shfl_down(a, o); o2 += __shfl_down(o2, o); }
    if (lane == 0) { fr0[wv] = a; fr1[wv] = o2; }
    __syncthreads();
    if (tid == 0) {
      ws->seedT[img] = fr0[0] + fr0[1] + fr0[2] + fr0[3];
      ws->seedOwn[img] = fr1[0] + fr1[1] + fr1[2] + fr1[3];
    }
  }
}

// ---------------- pass 3: medoid argmin (first-index tie-break via 64-bit key)
__global__ __launch_bounds__(256) void k_argmin(WS* __restrict__ ws) {
  int img = blockIdx.y;
  __shared__ unsigned long long skey[PAIRS];
  __shared__ float smx[PAIRS], smy[PAIRS];
  if (threadIdx.x < PAIRS) {
    skey[threadIdx.x] = ~0ULL;
    smx[threadIdx.x] = ws->medx[img][threadIdx.x];
    smy[threadIdx.x] = ws->medy[img][threadIdx.x];
  }
  __syncthreads();
  int px0 = blockIdx.x * 1024 + threadIdx.x * 4;
  uchar4 pr4 = *(const uchar4*)(ws->pridx[img] + px0);
  int y = px0 / WW;
  int x0 = px0 - y * WW;
  float by = basef(y);
#pragma unroll
  for (int k = 0; k < 4; k++) {
    int pr = (k == 0) ? pr4.x : (k == 1) ? pr4.y : (k == 2) ? pr4.z : pr4.w;
    if (pr != 255) {
      int pix = px0 + k;
      float dx = basef(x0 + k) - smx[pr];
      float dy = by - smy[pr];
      float d = dx * dx + dy * dy;
      unsigned long long key = ((unsigned long long)__float_as_uint(d) << 32) | (unsigned int)pix;
      atomicMin(&skey[pr], key);
    }
  }
  __syncthreads();
  if (threadIdx.x < PAIRS && skey[threadIdx.x] != ~0ULL)
    atomicMin(&ws->argkey[img][threadIdx.x], skey[threadIdx.x]);
}

// ---------------- pass 4 (heavy): ONE pixel pass, all 15 pairs/px, LDS hists
__global__ __launch_bounds__(256) void k_hist(const float* __restrict__ pred,
                                              WS* __restrict__ ws) {
  int img = blockIdx.y;
  int tid = threadIdx.x;
  __shared__ unsigned int h[PAIRS][2][BINS];   // 30720 B; [0]=out, [1]=in
  __shared__ float lvar[PAIRS], lseed[PAIRS];
  __shared__ float lm0[PAIRS], lm1[PAIRS];
  unsigned int* hf = &h[0][0][0];
#pragma unroll
  for (int k = 0; k < PAIRS * 2 * BINS / 256; k++) hf[k * 256 + tid] = 0;
  if (tid < PAIRS) {
    lvar[tid] = 0.f; lseed[tid] = 0.f;
    lm0[tid] = ws->sm0a[img][tid]; lm1[tid] = ws->sm1a[img][tid];
  }
  __syncthreads();

  // per-pair constants in registers (compile-time indices only)
  float cxr[PAIRS], cyr[PAIRS], S0r[PAIRS], S1r[PAIRS];
#pragma unroll
  for (int p = 0; p < PAIRS; p++) {
    unsigned long long key = ws->argkey[img][p];
    int imin = (int)(key & 0xffffffffu);
    cxr[p] = basef(imin % WW);
    cyr[p] = basef(imin / WW);
    S0r[p] = ws->s0a[img][p];
    S1r[p] = ws->s1a[img][p];
  }
  const float* pb = pred + (size_t)img * NCH * NPIX;
  const float* embb = (const float*)ws->emb[img];
  const unsigned char* prb = ws->pridx[img];
  int base = blockIdx.x * HPXB;

#pragma unroll 2
  for (int i = 0; i < HPXB / 256; i++) {       // 9 px/thread
    int pix = base + i * 256 + tid;
    float2 e = *(const float2*)(embb + 2 * pix);
    int pp = prb[pix];
    float dOwn = 0.f;
#pragma unroll
    for (int p = 0; p < PAIRS; p++) {
      float dx = e.x - cxr[p];
      float dy = e.y - cyr[p];
      float q = dx * dx * S0r[p] + dy * dy * S1r[p];
      float d = __expf(-q);
      bool m = (pp == p);
      dOwn = m ? d : dOwn;
      float e2 = d + d;
      float err = m ? (2.f - e2) : e2;
      int bin = (int)(err * (BINS * 0.5f));
      bin = bin > (BINS - 1) ? (BINS - 1) : (bin < 0 ? 0 : bin);
      atomicAdd(&h[p][m ? 1 : 0][bin], 1u);
    }
    if (pp != 255) {                            // fused var + seed_in (own pair)
      float g0 = pb[2 * NPIX + pix] - lm0[pp];
      float g1 = pb[3 * NPIX + pix] - lm1[pp];
      atomicAdd(&lvar[pp], g0 * g0 + g1 * g1);
      float sd = fast_sigmoid(pb[(4 + pp / MAXID) * NPIX + pix]) - dOwn;
      atomicAdd(&lseed[pp], sd * sd);
    }
  }
  __syncthreads();
  // packed u64 flush, skip zeros: 7680 u32 = 3840 u64, 15/thread
  unsigned long long* gh = (unsigned long long*)&ws->hall[img][0][0][0];
#pragma unroll
  for (int k = tid * 2; k < PAIRS * 2 * BINS; k += 512) {
    unsigned long long v = (unsigned long long)hf[k] |
                           ((unsigned long long)hf[k + 1] << 32);
    if (v) atomicAdd(&gh[k >> 1], v);
  }
  if (tid < PAIRS) {
    if (lvar[tid] != 0.f) atomicAdd(&ws->varsum[img][tid], lvar[tid]);
    if (lseed[tid] != 0.f) atomicAdd(&ws->seedin[img][tid], lseed[tid]);
  }
}

// ---------------- pass 5: lovasz (parallel suffix scan) + (last block) final combine
__global__ __launch_bounds__(256) void k_lovasz(WS* __restrict__ ws, float* __restrict__ out) {
  int b = blockIdx.x / PAIRS, p = blockIdx.x % PAIRS;
  unsigned int gts = ws->cnt[b][p];
  int tid = threadIdx.x;
  float lv = 0.f;
  __shared__ unsigned int sin_s[BINS], sout_s[BINS];
  if (gts != 0) {
    sin_s[tid] = ws->hall[b][p][1][tid];
    sout_s[tid] = ws->hall[b][p][0][tid];
    __syncthreads();
    for (int d = 1; d < BINS; d <<= 1) {     // inclusive suffix scan
      unsigned int a = (tid + d < BINS) ? sin_s[tid + d] : 0u;
      unsigned int c = (tid + d < BINS) ? sout_s[tid + d] : 0u;
      __syncthreads();
      sin_s[tid] += a; sout_s[tid] += c;
      __syncthreads();
    }
    float gtsf = (float)gts;
    float js = 0.f;
    if (tid >= 1) {
      unsigned int Sin = sin_s[tid], Sout = sout_s[tid];
      js = 1.f - (float)(gts - Sin) / (gtsf + (float)Sout);
    }
    for (int o = 32; o; o >>= 1) js += __shfl_down(js, o);
    __shared__ float wsum[4];
    if ((tid & 63) == 0) wsum[tid >> 6] = js;
    __syncthreads();
    if (tid == 0)
      lv = (2.f / BINS) * (0.5f + wsum[0] + wsum[1] + wsum[2] + wsum[3]);
  }
  __shared__ int amLast;
  if (tid == 0) {
    atomicExch(&ws->lov[b][p], lv);           // device-scope publish (G16)
    __threadfence();
    unsigned int old = atomicAdd(&ws->lovdone, 1u);
    amLast = (old == NIMG * PAIRS - 1);
  }
  __syncthreads();
  if (amLast) {
    __shared__ float rl[NIMG], rv[NIMG], rs[NIMG], ro[NIMG];
    if (tid < NIMG) { rl[tid] = 0.f; rv[tid] = 0.f; rs[tid] = 0.f; ro[tid] = 0.f; }
    __syncthreads();
    if (tid < NIMG * PAIRS) {                 // 30 CONCURRENT atomic reads
      int bb = tid / PAIRS, pp = tid % PAIRS;
      float vf = ws->validf[bb][pp];
      float lvv = atomicAdd(&ws->lov[bb][pp], 0.f);  // same-kernel cross-XCD read
      atomicAdd(&rl[bb], vf * lvv);
      atomicAdd(&rv[bb], vf * ws->varsum[bb][pp] / (ws->cntf[bb][pp] * 2.f));
      atomicAdd(&rs[bb], vf * ws->seedin[bb][pp]);
      atomicAdd(&ro[bb], vf);
    }
    __syncthreads();
    if (tid == 0) {
      float tot = 0.f;
      for (int bb = 0; bb < NIMG; bb++) {
        float objs = ro[bb] < 1.f ? 1.f : ro[bb];
        float seed_bg = ws->seedT[bb] - ws->seedOwn[bb];
        float seed_loss = (seed_bg + rs[bb]) / (float)NPIX;
        tot += rl[bb] / objs + 10.f * rv[bb] / objs + seed_loss;
      }
      out[0] = tot * 0.5f;
    }
  }
}

extern "C" void kernel_launch(void* const* d_in, const int* in_sizes, int n_in,
                              void* d_out, int out_size, void* d_ws, size_t ws_size,
                              hipStream_t stream) {
  const float* pred = (const float*)d_in[0];
  const int* inst = (const int*)d_in[1];
  const int* lab = (const int*)d_in[2];
  WS* ws = (WS*)d_ws;

  size_t zoff = offsetof(WS, cnt);
  size_t zend = offsetof(WS, medx);
  hipMemsetAsync((char*)d_ws, 0xFF, zoff, stream);                 // argmin keys -> u64 max
  hipMemsetAsync((char*)d_ws + zoff, 0, zend - zoff, stream);      // accumulators -> 0

  k_pass1<<<dim3(TX, TY, NIMG), 256, 0, stream>>>(pred, inst, lab, ws);
  k_medoid<<<dim3(NIMG * PAIRS), 256, 0, stream>>>(ws);
  k_argmin<<<dim3(NPIX / 1024, NIMG), 256, 0, stream>>>(ws);
  k_hist<<<dim3(HNB, NIMG), 256, 0, stream>>>(pred, ws);
  k_lovasz<<<dim3(NIMG * PAIRS), 256, 0, stream>>>(ws, (float*)d_out);
}

// Round 7
// 83.187 us; speedup vs baseline: 2.1428x; 1.1519x over previous
//
#include <hip/hip_runtime.h>
#include <cstddef>
#include <cstdint>

// SpatialEmbLoss on MI355X.
// H=W=768, 2 images, NC=5 classes, MAX_ID=3 -> 15 (class,id) pairs per image.
// Lovasz hinge via 256-bin error histogram:
//   lov = integral_0^2 jac(t) dt,  jac(t) = 1 - (gts - n_in(t))/(gts + n_out(t))
// Round 7: structural cleanup. (1) no memset nodes -- k_pass1 zeroes the
// accumulator region + inits argkeys. (2) k_argmin 64 blocks/img (was 576/img:
// 576-deep global atomicMin chains ~14us). (3) k_medoid reads TRANSPOSED
// partials (contiguous 64B per column, was 2768B-stride u16 loads). (4) k_hist
// u16-packed LDS hists (15.4KB) + 512-thread blocks for occupancy.

#define HH 768
#define WW 768
#define NPIX (HH*WW)            // 589824
#define NCL 5
#define MAXID 3
#define PAIRS (NCL*MAXID)       // 15
#define NIMG 2
#define NCH 9                   // 2 emb + 2 sigma + 5 seed channels
#define BINS 256
#define HPXB 2048               // pixels per k_hist block (4/thread @ 512 thr)
#define HNB (NPIX/HPXB)         // 288 blocks per image
#define TX 12                   // pass1 x-tiles (64 cols each)
#define TY 32                   // pass1 y-tiles (24 rows each)
#define XW 64
#define YH 24
#define BPI (TX*TY)             // 384 pass1 blocks per image
#define ANB 64                  // argmin blocks per image
#define APXB (NPIX/ANB)         // 9216 px per argmin block

struct WS {
  // ---------- zero region (zeroed by k_pass1 grid-stride every call) ----------
  alignas(8) unsigned int hall[NIMG][PAIRS][2][BINS];  // [0]=out, [1]=in
  float varsum[NIMG][PAIRS];
  float seedin[NIMG][PAIRS];
  unsigned int lovdone;
  unsigned int zpad[3];
  // ---------- end zero region ----------
  unsigned long long argkey[NIMG][PAIRS];   // ~0 init by pass1 blk0; atomicMin
  float medx[NIMG][PAIRS], medy[NIMG][PAIRS];
  float s0a[NIMG][PAIRS], s1a[NIMG][PAIRS];
  float sm0a[NIMG][PAIRS], sm1a[NIMG][PAIRS];
  float validf[NIMG][PAIRS], cntf[NIMG][PAIRS];
  float lov[NIMG][PAIRS];
  float seedT[NIMG], seedOwn[NIMG];
  unsigned int cnt[NIMG][PAIRS];
  alignas(16) float2 emb[NIMG][NPIX];      // {tanh(p0)+x, tanh(p1)+y}
  unsigned char pridx[NIMG][NPIX];         // pair index 0..14, 255 = none
  // transposed pass1 partials (atomic-free, contiguous reduce reads)
  alignas(64) unsigned short colpart[NIMG][PAIRS][WW][TY];  // [x][yt]
  alignas(64) unsigned short rowpart[NIMG][PAIRS][HH][TX];  // [y][xt]
  float sig0part[NIMG][PAIRS][BPI];
  float sig1part[NIMG][PAIRS][BPI];
  float sTpart[NIMG][BPI];
  float sOpart[NIMG][BPI];
};

__device__ __forceinline__ float basef(int i) {
  // jnp.linspace(0,1,1024)[i]
  return (float)i * (1.0f / 1023.0f);
}
__device__ __forceinline__ int pair_of(int l, int it) {
  return (l >= 1 && l <= NCL && it >= 1 && it <= MAXID) ? (l - 1) * MAXID + (it - 1) : -1;
}
__device__ __forceinline__ float fast_sigmoid(float z) {
  return __fdividef(1.f, 1.f + __expf(-z));
}
__device__ __forceinline__ float fast_tanh(float x) {
  float xc = fminf(fmaxf(x, -15.f), 15.f);
  float e = __expf(2.f * xc);
  return __fdividef(e - 1.f, e + 1.f);
}

// ---------------- pass 1: tile 64x24; LDS hists; transposed partial stores;
//                  also zeroes accumulator region + inits argkeys (no memsets)
__global__ __launch_bounds__(256) void k_pass1(const float* __restrict__ pred,
                                               const int* __restrict__ inst,
                                               const int* __restrict__ lab,
                                               WS* __restrict__ ws) {
  int img = blockIdx.z;
  int xt = blockIdx.x, yt = blockIdx.y;
  int x0 = xt * XW;
  int y0 = yt * YH;
  int tid = threadIdx.x, lane = tid & 63, wv = tid >> 6;

  // distributed zero of accumulator region + argkey init
  {
    const int ZN = (int)(offsetof(WS, argkey) / 4);   // u32 count
    int bid = (blockIdx.z * TY + blockIdx.y) * TX + blockIdx.x;
    int idx = bid * 256 + tid;
    if (idx < ZN) ((unsigned int*)ws)[idx] = 0u;
    if (bid == 0 && tid < NIMG * PAIRS)
      ((unsigned long long*)ws->argkey)[tid] = ~0ULL;
  }

  const float* p = pred + (size_t)img * NCH * NPIX;
  const int* lb = lab + (size_t)img * NPIX;
  const int* ib = inst + (size_t)img * NPIX;

  __shared__ unsigned int lcol[PAIRS][XW];
  __shared__ unsigned int lrow[PAIRS][YH];
  __shared__ float lsig0[PAIRS], lsig1[PAIRS];
  __shared__ float fred0[4], fred1[4];
  for (int k = tid; k < PAIRS * XW; k += 256) ((unsigned int*)lcol)[k] = 0;
  for (int k = tid; k < PAIRS * YH; k += 256) ((unsigned int*)lrow)[k] = 0;
  if (tid < PAIRS) { lsig0[tid] = 0.f; lsig1[tid] = 0.f; }
  __syncthreads();

  int x = x0 + lane;
  float bx = basef(x);
  float t = 0.f, own = 0.f;
#pragma unroll
  for (int i = 0; i < YH / 4; i++) {         // 6 rows per wave
    int y = y0 + wv + 4 * i;
    int pix = y * WW + x;
    int l = lb[pix];
    int it = ib[pix];
    float s, q;
    s = fast_sigmoid(p[4 * NPIX + pix]); q = s * s; t += q; if (l == 1) own += q;
    s = fast_sigmoid(p[5 * NPIX + pix]); q = s * s; t += q; if (l == 2) own += q;
    s = fast_sigmoid(p[6 * NPIX + pix]); q = s * s; t += q; if (l == 3) own += q;
    s = fast_sigmoid(p[7 * NPIX + pix]); q = s * s; t += q; if (l == 4) own += q;
    s = fast_sigmoid(p[8 * NPIX + pix]); q = s * s; t += q; if (l == 5) own += q;
    float e0 = fast_tanh(p[0 * NPIX + pix]) + bx;
    float e1 = fast_tanh(p[1 * NPIX + pix]) + basef(y);
    ws->emb[img][pix] = make_float2(e0, e1);
    int pr = pair_of(l, it);
    ws->pridx[img][pix] = (unsigned char)(pr >= 0 ? pr : 255);
    if (pr >= 0) {
      atomicAdd(&lcol[pr][lane], 1u);
      atomicAdd(&lrow[pr][y - y0], 1u);
      atomicAdd(&lsig0[pr], p[2 * NPIX + pix]);
      atomicAdd(&lsig1[pr], p[3 * NPIX + pix]);
    }
  }
  // seed scalars: wave reduce -> LDS
  for (int o = 32; o; o >>= 1) { t += __shfl_down(t, o); own += __shfl_down(own, o); }
  if (lane == 0) { fred0[wv] = t; fred1[wv] = own; }
  __syncthreads();

  // transposed partial flush (plain stores; byte-granular writes are safe)
  int bi = yt * TX + xt;                     // 0..BPI-1 within image
  for (int k = tid; k < PAIRS * XW; k += 256) {
    int pp = k >> 6, c = k & 63;
    ws->colpart[img][pp][x0 + c][yt] = (unsigned short)lcol[pp][c];
  }
  for (int k = tid; k < PAIRS * YH; k += 256) {
    int pp = k / YH, r = k % YH;
    ws->rowpart[img][pp][y0 + r][xt] = (unsigned short)lrow[pp][r];
  }
  if (tid < PAIRS) {
    ws->sig0part[img][tid][bi] = lsig0[tid];
    ws->sig1part[img][tid][bi] = lsig1[tid];
  }
  if (tid == 0) {
    ws->sTpart[img][bi] = fred0[0] + fred0[1] + fred0[2] + fred0[3];
    ws->sOpart[img][bi] = fred1[0] + fred1[1] + fred1[2] + fred1[3];
  }
}

// ---------------- pass 2: medians (transposed-partial reduce + block scan),
//                  sigma means, cnt, validf, seed totals
__global__ __launch_bounds__(256) void k_medoid(WS* __restrict__ ws) {
  int img = blockIdx.x / PAIRS, p = blockIdx.x % PAIRS;
  int tid = threadIdx.x, lane = tid & 63, wv = tid >> 6;
  __shared__ unsigned int pref[256];
  __shared__ int cross;
  __shared__ float fr0[4], fr1[4];
  unsigned int c = 0;
  int res[2];
#pragma unroll
  for (int h = 0; h < 2; h++) {
    unsigned int v[3];
#pragma unroll
    for (int j = 0; j < 3; j++) {
      int cc = tid * 3 + j;      // col or row index 0..767
      unsigned int s = 0;
      if (h == 0) {              // 32 contiguous u16 = 16 u32
        const unsigned int* w = (const unsigned int*)ws->colpart[img][p][cc];
#pragma unroll
        for (int i = 0; i < TY / 2; i++) { unsigned int u = w[i]; s += (u & 0xFFFFu) + (u >> 16); }
      } else {                   // 12 contiguous u16 = 6 u32
        const unsigned int* w = (const unsigned int*)ws->rowpart[img][p][cc];
#pragma unroll
        for (int i = 0; i < TX / 2; i++) { unsigned int u = w[i]; s += (u & 0xFFFFu) + (u >> 16); }
      }
      v[j] = s;
    }
    unsigned int s3 = v[0] + v[1] + v[2];
    pref[tid] = s3;
    __syncthreads();
    for (int d = 1; d < 256; d <<= 1) {
      unsigned int tv = (tid >= d) ? pref[tid - d] : 0u;
      __syncthreads();
      pref[tid] += tv;
      __syncthreads();
    }
    c = pref[255];
    unsigned int target = (c > 0) ? (((c - 1u) >> 1) + 1u) : 1u;
    if (tid == 0) cross = 0;
    __syncthreads();
    unsigned int inc = pref[tid];
    unsigned int exc = inc - s3;
    if (inc >= target && exc < target) {
      int j = (exc + v[0] >= target) ? 0 : ((exc + v[0] + v[1] >= target) ? 1 : 2);
      cross = tid * 3 + j;
    }
    __syncthreads();
    res[h] = cross;
    __syncthreads();
  }
  // sigma sums over 384 contiguous partials
  float s0 = 0.f, s1 = 0.f;
  for (int b = tid; b < BPI; b += 256) { s0 += ws->sig0part[img][p][b]; s1 += ws->sig1part[img][p][b]; }
  for (int o = 32; o; o >>= 1) { s0 += __shfl_down(s0, o); s1 += __shfl_down(s1, o); }
  if (lane == 0) { fr0[wv] = s0; fr1[wv] = s1; }
  __syncthreads();
  if (tid == 0) {
    float sig0 = fr0[0] + fr0[1] + fr0[2] + fr0[3];
    float sig1 = fr1[0] + fr1[1] + fr1[2] + fr1[3];
    float vf = (c > 0) ? 1.f : 0.f;
    float cf = (c > 0) ? (float)c : 1.f;
    float sm0 = sig0 / cf, sm1 = sig1 / cf;
    ws->cnt[img][p] = c;
    ws->medx[img][p] = basef(res[0]);
    ws->medy[img][p] = basef(res[1]);
    ws->sm0a[img][p] = sm0;
    ws->sm1a[img][p] = sm1;
    ws->s0a[img][p] = __expf(10.f * sm0);
    ws->s1a[img][p] = __expf(10.f * sm1);
    ws->validf[img][p] = vf;
    ws->cntf[img][p] = cf;
  }
  __syncthreads();
  if (p == 0) {      // seed totals, once per image
    float a = 0.f, o2 = 0.f;
    for (int b = tid; b < BPI; b += 256) { a += ws->sTpart[img][b]; o2 += ws->sOpart[img][b]; }
    for (int o = 32; o; o >>= 1) { a += __shfl_down(a, o); o2 += __shfl_down(o2, o); }
    if (lane == 0) { fr0[wv] = a; fr1[wv] = o2; }
    __syncthreads();
    if (tid == 0) {
      ws->seedT[img] = fr0[0] + fr0[1] + fr0[2] + fr0[3];
      ws->seedOwn[img] = fr1[0] + fr1[1] + fr1[2] + fr1[3];
    }
  }
}

// ---------------- pass 3: medoid argmin; 64 blocks/img -> shallow global chains
__global__ __launch_bounds__(256) void k_argmin(WS* __restrict__ ws) {
  int img = blockIdx.y;
  __shared__ unsigned long long skey[PAIRS];
  __shared__ float smx[PAIRS], smy[PAIRS];
  if (threadIdx.x < PAIRS) {
    skey[threadIdx.x] = ~0ULL;
    smx[threadIdx.x] = ws->medx[img][threadIdx.x];
    smy[threadIdx.x] = ws->medy[img][threadIdx.x];
  }
  __syncthreads();
  int base = blockIdx.x * APXB;
#pragma unroll
  for (int i = 0; i < APXB / 1024; i++) {    // 9 iters x 4 px
    int px0 = base + i * 1024 + threadIdx.x * 4;
    uchar4 pr4 = *(const uchar4*)(ws->pridx[img] + px0);
    int y = px0 / WW;
    int x0 = px0 - y * WW;
    float by = basef(y);
#pragma unroll
    for (int k = 0; k < 4; k++) {
      int pr = (k == 0) ? pr4.x : (k == 1) ? pr4.y : (k == 2) ? pr4.z : pr4.w;
      if (pr != 255) {
        int pix = px0 + k;
        float dx = basef(x0 + k) - smx[pr];
        float dy = by - smy[pr];
        float d = dx * dx + dy * dy;
        unsigned long long key = ((unsigned long long)__float_as_uint(d) << 32) | (unsigned int)pix;
        atomicMin(&skey[pr], key);
      }
    }
  }
  __syncthreads();
  if (threadIdx.x < PAIRS && skey[threadIdx.x] != ~0ULL)
    atomicMin(&ws->argkey[img][threadIdx.x], skey[threadIdx.x]);
}

// ---------------- pass 4 (heavy): ONE pixel pass, all 15 pairs/px,
//                  u16-packed LDS hists (max count/block 2048 < 2^16)
__global__ __launch_bounds__(512) void k_hist(const float* __restrict__ pred,
                                              WS* __restrict__ ws) {
  int img = blockIdx.y;
  int tid = threadIdx.x;
  __shared__ unsigned int h32[PAIRS * 2 * (BINS / 2)];   // 15360 B
  __shared__ float lvar[PAIRS], lseed[PAIRS];
  __shared__ float lm0[PAIRS], lm1[PAIRS];
  for (int k = tid; k < PAIRS * 2 * (BINS / 2); k += 512) h32[k] = 0;
  if (tid < PAIRS) {
    lvar[tid] = 0.f; lseed[tid] = 0.f;
    lm0[tid] = ws->sm0a[img][tid]; lm1[tid] = ws->sm1a[img][tid];
  }
  __syncthreads();

  // per-pair constants in registers (compile-time indices only)
  float cxr[PAIRS], cyr[PAIRS], S0r[PAIRS], S1r[PAIRS];
#pragma unroll
  for (int p = 0; p < PAIRS; p++) {
    unsigned long long key = ws->argkey[img][p];
    int imin = (int)(key & 0xffffffffu);
    cxr[p] = basef(imin % WW);
    cyr[p] = basef(imin / WW);
    S0r[p] = ws->s0a[img][p];
    S1r[p] = ws->s1a[img][p];
  }
  const float* pb = pred + (size_t)img * NCH * NPIX;
  const float* embb = (const float*)ws->emb[img];
  const unsigned char* prb = ws->pridx[img];
  int base = blockIdx.x * HPXB;

#pragma unroll
  for (int i = 0; i < HPXB / 512; i++) {       // 4 px/thread
    int pix = base + i * 512 + tid;
    float2 e = *(const float2*)(embb + 2 * pix);
    int pp = prb[pix];
    float dOwn = 0.f;
#pragma unroll
    for (int p = 0; p < PAIRS; p++) {
      float dx = e.x - cxr[p];
      float dy = e.y - cyr[p];
      float q = dx * dx * S0r[p] + dy * dy * S1r[p];
      float d = __expf(-q);
      bool m = (pp == p);
      dOwn = m ? d : dOwn;
      int ib = (int)fminf(d * 256.f, 255.f);   // out-bin; in-bin = 255-ib
      int bin = m ? (255 - ib) : ib;
      int hidx = (p * 2 + (m ? 1 : 0)) * BINS + bin;
      atomicAdd(&h32[hidx >> 1], 1u << ((hidx & 1) * 16));
    }
    if (pp != 255) {                            // fused var + seed_in (own pair)
      float g0 = pb[2 * NPIX + pix] - lm0[pp];
      float g1 = pb[3 * NPIX + pix] - lm1[pp];
      atomicAdd(&lvar[pp], g0 * g0 + g1 * g1);
      float sd = fast_sigmoid(pb[(4 + pp / MAXID) * NPIX + pix]) - dOwn;
      atomicAdd(&lseed[pp], sd * sd);
    }
  }
  __syncthreads();
  // unpack u16 pairs -> packed u64 global atomics; skip zeros
  unsigned long long* gh = (unsigned long long*)&ws->hall[img][0][0][0];
  for (int k = tid; k < PAIRS * 2 * (BINS / 2); k += 512) {
    unsigned int w = h32[k];
    if (w) {
      unsigned long long v = (unsigned long long)(w & 0xFFFFu) |
                             ((unsigned long long)(w >> 16) << 32);
      atomicAdd(&gh[k], v);
    }
  }
  if (tid < PAIRS) {
    if (lvar[tid] != 0.f) atomicAdd(&ws->varsum[img][tid], lvar[tid]);
    if (lseed[tid] != 0.f) atomicAdd(&ws->seedin[img][tid], lseed[tid]);
  }
}

// ---------------- pass 5: lovasz (parallel suffix scan) + (last block) final combine
__global__ __launch_bounds__(256) void k_lovasz(WS* __restrict__ ws, float* __restrict__ out) {
  int b = blockIdx.x / PAIRS, p = blockIdx.x % PAIRS;
  unsigned int gts = ws->cnt[b][p];
  int tid = threadIdx.x;
  float lv = 0.f;
  __shared__ unsigned int sin_s[BINS], sout_s[BINS];
  if (gts != 0) {
    sin_s[tid] = ws->hall[b][p][1][tid];
    sout_s[tid] = ws->hall[b][p][0][tid];
    __syncthreads();
    for (int d = 1; d < BINS; d <<= 1) {     // inclusive suffix scan
      unsigned int a = (tid + d < BINS) ? sin_s[tid + d] : 0u;
      unsigned int c = (tid + d < BINS) ? sout_s[tid + d] : 0u;
      __syncthreads();
      sin_s[tid] += a; sout_s[tid] += c;
      __syncthreads();
    }
    float gtsf = (float)gts;
    float js = 0.f;
    if (tid >= 1) {
      unsigned int Sin = sin_s[tid], Sout = sout_s[tid];
      js = 1.f - (float)(gts - Sin) / (gtsf + (float)Sout);
    }
    for (int o = 32; o; o >>= 1) js += __shfl_down(js, o);
    __shared__ float wsum[4];
    if ((tid & 63) == 0) wsum[tid >> 6] = js;
    __syncthreads();
    if (tid == 0)
      lv = (2.f / BINS) * (0.5f + wsum[0] + wsum[1] + wsum[2] + wsum[3]);
  }
  __shared__ int amLast;
  if (tid == 0) {
    atomicExch(&ws->lov[b][p], lv);           // device-scope publish (G16)
    __threadfence();
    unsigned int old = atomicAdd(&ws->lovdone, 1u);
    amLast = (old == NIMG * PAIRS - 1);
  }
  __syncthreads();
  if (amLast) {
    __shared__ float rl[NIMG], rv[NIMG], rs[NIMG], ro[NIMG];
    if (tid < NIMG) { rl[tid] = 0.f; rv[tid] = 0.f; rs[tid] = 0.f; ro[tid] = 0.f; }
    __syncthreads();
    if (tid < NIMG * PAIRS) {                 // 30 CONCURRENT atomic reads
      int bb = tid / PAIRS, pp = tid % PAIRS;
      float vf = ws->validf[bb][pp];
      float lvv = atomicAdd(&ws->lov[bb][pp], 0.f);  // same-kernel cross-XCD read
      atomicAdd(&rl[bb], vf * lvv);
      atomicAdd(&rv[bb], vf * ws->varsum[bb][pp] / (ws->cntf[bb][pp] * 2.f));
      atomicAdd(&rs[bb], vf * ws->seedin[bb][pp]);
      atomicAdd(&ro[bb], vf);
    }
    __syncthreads();
    if (tid == 0) {
      float tot = 0.f;
      for (int bb = 0; bb < NIMG; bb++) {
        float objs = ro[bb] < 1.f ? 1.f : ro[bb];
        float seed_bg = ws->seedT[bb] - ws->seedOwn[bb];
        float seed_loss = (seed_bg + rs[bb]) / (float)NPIX;
        tot += rl[bb] / objs + 10.f * rv[bb] / objs + seed_loss;
      }
      out[0] = tot * 0.5f;
    }
  }
}

extern "C" void kernel_launch(void* const* d_in, const int* in_sizes, int n_in,
                              void* d_out, int out_size, void* d_ws, size_t ws_size,
                              hipStream_t stream) {
  const float* pred = (const float*)d_in[0];
  const int* inst = (const int*)d_in[1];
  const int* lab = (const int*)d_in[2];
  WS* ws = (WS*)d_ws;

  k_pass1<<<dim3(TX, TY, NIMG), 256, 0, stream>>>(pred, inst, lab, ws);
  k_medoid<<<dim3(NIMG * PAIRS), 256, 0, stream>>>(ws);
  k_argmin<<<dim3(ANB, NIMG), 256, 0, stream>>>(ws);
  k_hist<<<dim3(HNB, NIMG), 512, 0, stream>>>(pred, ws);
  k_lovasz<<<dim3(NIMG * PAIRS), 256, 0, stream>>>(ws, (float*)d_out);
}